// Round 3
// baseline (125.638 us; speedup 1.0000x reference)
//
#include <hip/hip_runtime.h>
#include <hip/hip_bf16.h>
#include <math.h>

// GAT layer B=8, N=2048, F=64 on gfx950.
// Round 3: barrier-free, LDS-free k_attn — one wave per 16-row i-tile.
// P(i,j) is generated by the same thread that owns the MFMA A-fragment
// element (A[m=lane&15][k=quad*8+jj]), so P lives only in registers.
// B-fragments stream from L2 (whtg is 2 MB, L2-resident).
// k_pre fuses adj->bitmask (blocks 0..1023) and Wh/e1/e2 (blocks 1024..1279).

#define NN 2048
#define BB 8
#define ALPHA 0.2f

typedef __attribute__((ext_vector_type(8))) short s8v;   // 8 bf16 = 4 VGPRs
typedef __attribute__((ext_vector_type(4))) float f4v;

static __device__ __forceinline__ unsigned pk_bf16(float lo, float hi) {
  __hip_bfloat162 t = __float22bfloat162_rn(float2{lo, hi});
  return *(unsigned*)&t;
}

// ---------------- Kernel 1: fused adj-bitmask + Wh/e1/e2 ----------------
__global__ __launch_bounds__(512) void k_pre(
    const float* __restrict__ adj, const float* __restrict__ h,
    const float* __restrict__ W, const float* __restrict__ a,
    unsigned long long* __restrict__ adjq, unsigned short* __restrict__ whtg,
    float* __restrict__ e1, float* __restrict__ e2) {
  const int t = threadIdx.x, lane = t & 63, w = t >> 6;

  if (blockIdx.x < 1024) {
    // ---- part A: adj -> bit rows (2 rows per block) ----
    const int row = blockIdx.x * 2 + (w >> 2);
    const int wq = w & 3;
    #pragma unroll
    for (int it = 0; it < 8; ++it) {
      const int j = wq * 512 + it * 64 + lane;
      unsigned long long m = __ballot(adj[(size_t)row * NN + j] > 0.f);
      if (lane == 0) adjq[row * 32 + wq * 8 + it] = m;
    }
    return;
  }

  // ---- part B: Wh (bf16, transposed [B,64,N]) + e1,e2 ; 64 rows/block ----
  __shared__ __align__(16) float hsAll[64][68];
  __shared__ __align__(16) unsigned short Ws[64][72];
  const int rowBase = (blockIdx.x - 1024) * 64;
  const int b = rowBase >> 11, n0 = rowBase & (NN - 1);

  float wr[64];                                  // W row `lane` (o = lane)
  #pragma unroll
  for (int k = 0; k < 16; ++k)
    *(f4v*)&wr[k * 4] = *(const f4v*)&W[lane * 64 + k * 4];

  #pragma unroll
  for (int qq = 0; qq < 2; ++qq) {
    const int idx = t + 512 * qq;                // 1024 float4s
    const int r = idx >> 4, c = (idx & 15) * 4;
    *(f4v*)&hsAll[r][c] = *(const f4v*)&h[(size_t)(rowBase + r) * 64 + c];
  }
  const float a1v = a[lane], a2v = a[64 + lane];
  __syncthreads();

  const int r0 = w * 8;                          // 8 rows per wave
  float acc[8];
  #pragma unroll
  for (int rr = 0; rr < 8; ++rr) acc[rr] = 0.f;
  #pragma unroll
  for (int f4i = 0; f4i < 16; ++f4i) {
    f4v hv[8];
    #pragma unroll
    for (int rr = 0; rr < 8; ++rr) hv[rr] = *(const f4v*)&hsAll[r0 + rr][f4i * 4];
    #pragma unroll
    for (int x = 0; x < 4; ++x) {
      const float wv = wr[f4i * 4 + x];
      #pragma unroll
      for (int rr = 0; rr < 8; ++rr) acc[rr] = fmaf(hv[rr][x], wv, acc[rr]);
    }
  }
  #pragma unroll
  for (int p = 0; p < 4; ++p)
    *(unsigned*)&Ws[lane][r0 + p * 2] = pk_bf16(acc[p * 2], acc[p * 2 + 1]);

  float s1[8], s2[8];
  #pragma unroll
  for (int rr = 0; rr < 8; ++rr) { s1[rr] = acc[rr] * a1v; s2[rr] = acc[rr] * a2v; }
  #pragma unroll
  for (int m = 1; m < 64; m <<= 1)
    #pragma unroll
    for (int rr = 0; rr < 8; ++rr) {
      s1[rr] += __shfl_xor(s1[rr], m);
      s2[rr] += __shfl_xor(s2[rr], m);
    }
  if (lane == 0)
    #pragma unroll
    for (int rr = 0; rr < 8; ++rr) {
      e1[rowBase + r0 + rr] = s1[rr];
      e2[rowBase + r0 + rr] = s2[rr];
    }
  __syncthreads();

  // transposed coalesced store: 128 B contiguous per o
  const int o = t >> 3, seg = t & 7;
  const s8v v = *(const s8v*)&Ws[o][seg * 8];
  *(s8v*)(whtg + ((size_t)(b * 64 + o) << 11) + n0 + seg * 8) = v;
}

// ---------------- Kernel 2: fused attention, barrier-free ----------------
// Grid (N/16, B) = (128, 8), 64 threads (one wave). No LDS, no barriers.
__global__ __launch_bounds__(64) void k_attn(
    const unsigned long long* __restrict__ adjq,
    const unsigned short* __restrict__ whtg,
    const float* __restrict__ e1g, const float* __restrict__ e2g,
    float* __restrict__ out) {
  const int lane = threadIdx.x;
  const int q = lane >> 4, l15 = lane & 15;
  const int b = blockIdx.y;
  const int i0 = blockIdx.x * 16;
  const size_t bN = (size_t)b * NN;

  const float e1v = e1g[bN + i0 + l15];
  const unsigned long long* arow = adjq + (size_t)(i0 + l15) * 32;
  const unsigned short* wb = whtg + ((size_t)b << 17);   // b*64*2048

  f4v acc[4];
  #pragma unroll
  for (int s = 0; s < 4; ++s) acc[s] = f4v{0.f, 0.f, 0.f, 0.f};
  float psum = 0.f;

  // prefetch tile-0 scalars
  unsigned long long am = arow[0];
  f4v e2r[4];
  #pragma unroll
  for (int ks = 0; ks < 2; ++ks)
    #pragma unroll
    for (int hh = 0; hh < 2; ++hh)
      e2r[ks * 2 + hh] = *(const f4v*)&e2g[bN + ks * 32 + q * 8 + hh * 4];

  for (int jt = 0; jt < 32; ++jt) {
    const int j0 = jt * 64;
    // B-fragments for this tile straight from L2 (16 B/lane, contiguous)
    s8v bfr[8];
    #pragma unroll
    for (int s = 0; s < 4; ++s)
      #pragma unroll
      for (int ks = 0; ks < 2; ++ks)
        bfr[s * 2 + ks] =
            *(const s8v*)(wb + (((size_t)(s * 16 + l15)) << 11) + j0 + ks * 32 + q * 8);

    // P-gen (registers only) -> A-fragments
    s8v af[2];
    #pragma unroll
    for (int ks = 0; ks < 2; ++ks) {
      const unsigned bits = (unsigned)(am >> (ks * 32 + q * 8)) & 0xffu;
      float p[8];
      #pragma unroll
      for (int jj = 0; jj < 8; ++jj) {
        const float s = e1v + e2r[ks * 2 + (jj >> 2)][jj & 3];
        const float lr = fmaxf(s, ALPHA * s);
        const float pv = ((bits >> jj) & 1u) ? __expf(lr) : 0.f;
        p[jj] = pv;
        psum += pv;
      }
      union { s8v v; unsigned u[4]; } cv;
      cv.u[0] = pk_bf16(p[0], p[1]);
      cv.u[1] = pk_bf16(p[2], p[3]);
      cv.u[2] = pk_bf16(p[4], p[5]);
      cv.u[3] = pk_bf16(p[6], p[7]);
      af[ks] = cv.v;
    }

    // prefetch next tile scalars (after use, before MFMA)
    if (jt < 31) {
      am = arow[jt + 1];
      const int jn = j0 + 64;
      #pragma unroll
      for (int ks = 0; ks < 2; ++ks)
        #pragma unroll
        for (int hh = 0; hh < 2; ++hh)
          e2r[ks * 2 + hh] = *(const f4v*)&e2g[bN + jn + ks * 32 + q * 8 + hh * 4];
    }

    #pragma unroll
    for (int s = 0; s < 4; ++s) {
      acc[s] = __builtin_amdgcn_mfma_f32_16x16x32_bf16(af[0], bfr[s * 2 + 0], acc[s], 0, 0, 0);
      acc[s] = __builtin_amdgcn_mfma_f32_16x16x32_bf16(af[1], bfr[s * 2 + 1], acc[s], 0, 0, 0);
    }
  }

  // row sums: lanes {l15, l15+16, l15+32, l15+48} partition row l15
  psum += __shfl_xor(psum, 16);
  psum += __shfl_xor(psum, 32);
  float rs[4];
  #pragma unroll
  for (int r = 0; r < 4; ++r) rs[r] = __shfl(psum, q * 4 + r);   // rowsum(q*4+r)

  // epilogue: C/D row = q*4+reg, col = l15 (m89 layout)
  #pragma unroll
  for (int s = 0; s < 4; ++s)
    #pragma unroll
    for (int r = 0; r < 4; ++r) {
      float v = acc[s][r] / rs[r];
      v = v > 0.f ? v : expm1f(v);
      out[(bN + i0 + q * 4 + r) * 64 + s * 16 + l15] = v;
    }
}

extern "C" void kernel_launch(void* const* d_in, const int* in_sizes, int n_in,
                              void* d_out, int out_size, void* d_ws, size_t ws_size,
                              hipStream_t stream) {
  (void)in_sizes; (void)n_in; (void)out_size; (void)ws_size;
  const float* h   = (const float*)d_in[0];
  const float* adj = (const float*)d_in[1];
  const float* W   = (const float*)d_in[2];
  const float* a   = (const float*)d_in[3];
  float* outp = (float*)d_out;

  // ws carve: whtg 2 MB | e1 64 KB | e2 64 KB | adjq 512 KB
  unsigned short* whtg = (unsigned short*)d_ws;
  float* e1 = (float*)((char*)d_ws + (size_t)BB * 64 * NN * 2);
  float* e2 = e1 + (size_t)BB * NN;
  unsigned long long* adjq = (unsigned long long*)(e2 + (size_t)BB * NN);

  k_pre<<<1280, 512, 0, stream>>>(adj, h, W, a, adjq, whtg, e1, e2);
  k_attn<<<dim3(NN / 16, BB), 64, 0, stream>>>(adjq, whtg, e1, e2, outp);
}